// Round 5
// baseline (2806.023 us; speedup 1.0000x reference)
//
#include <hip/hip_runtime.h>
#include <hip/hip_bf16.h>

// Problem constants
#define C1c 256
#define C2c 256
#define NBAT 16
#define HH 56
#define WW 56
#define KS 13
#define PADc 6
#define HP 68                    // 56 + 2*6
#define NPIX (NBAT*HH*WW)        // 50176
#define PIXTILES 196             // NPIX / 256
#define KSTEPS2 1352             // 169 * 8 steps of BK=32, order (kh, q, kw)

typedef __bf16 bf16;
typedef bf16 bf16x8 __attribute__((ext_vector_type(8)));
typedef float floatx4 __attribute__((ext_vector_type(4)));

// Workspace layout (bf16):
//   xT : [NBAT*HP*HP][C1]          = 18,939,904 elems (37,879,808 B)
//   wT : [1352][256][32]           = 11,075,584 elems (22,151,168 B)
#define XT_ELEMS ((size_t)NBAT*HP*HP*C1c)
#define WT_ELEMS ((size_t)KSTEPS2*256*32)

// ---------------------------------------------------------------------------
// Pre-pass 1: x (N,C,H,W) fp32 -> xT [(n*68+hp)*68+wp][c1] bf16, padded.
// ---------------------------------------------------------------------------
__global__ __launch_bounds__(256) void xform_x(const float* __restrict__ x,
                                               bf16* __restrict__ xT) {
  __shared__ bf16 tile[56][258];
  const int tid = threadIdx.x;
  const int n = blockIdx.x / HP;
  const int hp = blockIdx.x - n * HP;
  const int ih = hp - PADc;
  const size_t pos_base = (size_t)(n * HP + hp) * HP * C1c;

  if (ih < 0 || ih >= HH) {
#pragma unroll 1
    for (int i = tid; i < HP * 32; i += 256) {
      int wp = i >> 5, g = i & 31;
      *(uint4*)(xT + pos_base + wp * C1c + g * 8) = (uint4){0u, 0u, 0u, 0u};
    }
    return;
  }

  const int wave = tid >> 6, lane = tid & 63;
#pragma unroll 4
  for (int i = 0; i < 64; ++i) {
    int c = i * 4 + wave;                       // covers 0..255 exactly
    if (lane < WW) {
      float v = x[(((size_t)n * C1c + c) * HH + ih) * WW + lane];
      tile[lane][c] = (bf16)v;
    }
  }
  __syncthreads();

#pragma unroll 1
  for (int i = tid; i < HP * 32; i += 256) {
    int wp = i >> 5, g = i & 31;
    int iw = wp - PADc;
    uint4 o;
    if (iw >= 0 && iw < WW) {
      const uint* lp = (const uint*)&tile[iw][g * 8];   // dword-aligned
      o.x = lp[0]; o.y = lp[1]; o.z = lp[2]; o.w = lp[3];
    } else {
      o = (uint4){0u, 0u, 0u, 0u};
    }
    *(uint4*)(xT + pos_base + wp * C1c + g * 8) = o;
  }
}

// ---------------------------------------------------------------------------
// Pre-pass 2: w (C2,C1,13,13) fp32 -> wT [kk][c2][32] bf16
//   kk = (kh*8 + q)*13 + kw,  c1 = q*32 + e   (kw innermost for xT L2 reuse)
// ---------------------------------------------------------------------------
__global__ __launch_bounds__(256) void xform_w(const float* __restrict__ w,
                                               bf16* __restrict__ wT) {
  int j = blockIdx.x * 256 + threadIdx.x;   // KSTEPS2*256*4 threads
  int part = j & 3;
  int c2 = (j >> 2) & 255;
  int kk = j >> 10;            // 0..1351
  int kw = kk % 13;
  int t = kk / 13;
  int q = t & 7;
  int kh = t >> 3;
  int c1 = q * 32 + part * 8;
  const float* wp = w + ((size_t)c2 * C1c + c1) * (KS * KS) + kh * KS + kw;
  bf16x8 v;
#pragma unroll
  for (int i = 0; i < 8; i++) v[i] = (bf16)wp[(size_t)i * KS * KS];
  *(bf16x8*)(wT + (size_t)j * 8) = v;
}

// ---------------------------------------------------------------------------
// Main: implicit-GEMM conv + BN + SiLU.
//   Block tile: 256 c2 x 256 pixels, BK=32, 4 waves (2M x 2N),
//   per-wave 128x128: 8x8 mfma_f32_16x16x32_bf16 frags, acc = 256 AGPR.
//   Register double-buffer with publish-correct ring-4 (prefetch dist 3):
//   per step k: {read frags k+1 (its buffer was PUBLISHED by the barrier at
//   end of step k-1, since gloads were issued at step k-2) -> issue 8 gloads
//   for k+3 -> sched_barrier -> 64 MFMA on step-k regs -> vmcnt(8) (leaves
//   only the just-issued 8 outstanding => k+1 AND k+2 landed) -> s_barrier
//   (publishes)}. MFMA burst never waits on same-step LDS.
//   R4 bugfixes: staging dest stride i*2048 (64-row issues @256 thr; i*4096
//   overflowed the buffers), and vmcnt->barrier publish pairing restored.
//   1 wave/SIMD (reg budget 512: 256 acc + ~128 frag + addr).
//   XOR swizzle slot = part ^ ((row>>1)&3) on source addresses (proven 0-cf).
//   Grid = 196 blocks, bijective XCD swizzle (q=24, r=4).
// ---------------------------------------------------------------------------
__device__ __forceinline__ void gload_lds16(const bf16* g, bf16* l) {
  __builtin_amdgcn_global_load_lds(
      (const __attribute__((address_space(1))) void*)(g),
      (__attribute__((address_space(3))) void*)(l),
      16, 0, 0);
}

__global__ __launch_bounds__(256, 1) void conv_mfma(
    const bf16* __restrict__ xT, const bf16* __restrict__ wT,
    const float* __restrict__ gamma, const float* __restrict__ beta,
    const float* __restrict__ rmean, const float* __restrict__ rvar,
    float* __restrict__ out) {
  __shared__ __attribute__((aligned(16))) bf16 As[4][256 * 32];
  __shared__ __attribute__((aligned(16))) bf16 Bs[4][256 * 32];
  __shared__ float sS[256];
  __shared__ float sB[256];

  const int tid = threadIdx.x;
  const int lane = tid & 63;
  const int wave = tid >> 6;           // 0..3
  const int wm = wave >> 1, wn = wave & 1;

  // bijective XCD swizzle over 196 workgroups: q=24, r=4
  const int orig = blockIdx.x;
  const int xcd = orig & 7, kb = orig >> 3;
  const int pixt = (xcd < 4 ? xcd * 25 : 100 + (xcd - 4) * 24) + kb;
  const int pixbase = pixt * 256;

  // BN scale/bias for all 256 c2 rows
  {
    float s = gamma[tid] * rsqrtf(rvar[tid] + 1e-5f);
    sS[tid] = s;
    sB[tid] = beta[tid] - rmean[tid] * s;
  }
  __syncthreads();

  // --- staging lane constants (XOR-swizzled source granule) ---
  const int part = tid & 3;                  // LDS slot within 64B row
  const int row0 = tid >> 2;                 // 0..63: row within a 64-row issue
  const int srcg = (part ^ ((row0 >> 1) & 3)) * 8;  // source granule elems

  // A: issue i covers c2 rows [i*64, i*64+64)
  int aOffs[4];
#pragma unroll
  for (int i = 0; i < 4; i++) aOffs[i] = (i * 64 + row0) * 32 + srcg;

  // B: issue i covers pixels [pixbase + i*64, +64)
  int pOffs[4];
#pragma unroll
  for (int i = 0; i < 4; i++) {
    int pix = pixbase + i * 64 + row0;
    int n = pix / (HH * WW);
    int rr = pix - n * (HH * WW);
    int oh = rr / WW;
    int ow = rr - oh * WW;
    pOffs[i] = ((n * HP + oh) * HP + ow) * C1c + srcg;
  }

  // per-wave LDS destination base, in elems (gload dest = base + lane*16B)
  const int ldsW = wave * 512;

  // fragment-read lane constants (proven conflict-free pattern)
  const int mrow = lane & 15;
  const int kq = lane >> 4;                        // source k granule (0..3)
  const int g0 = (kq ^ ((mrow >> 1) & 3)) * 8;     // swizzled LDS offset
  const int aRB = (wm * 128 + mrow) * 32 + g0;     // + mi*512
  const int bRB = (wn * 128 + mrow) * 32 + g0;     // + ni*512

  floatx4 acc[8][8];
#pragma unroll
  for (int mi = 0; mi < 8; mi++)
#pragma unroll
    for (int ni = 0; ni < 8; ni++) acc[mi][ni] = (floatx4){0.f, 0.f, 0.f, 0.f};

  // prologue: stage steps 0,1,2 -> bufs 0,1,2 (step s: bOn = s*C1c, kw=s)
#pragma unroll
  for (int s = 0; s < 3; s++) {
#pragma unroll
    for (int i = 0; i < 4; i++)
      gload_lds16(wT + s * 8192 + aOffs[i], &As[s][i * 2048 + ldsW]);
#pragma unroll
    for (int i = 0; i < 4; i++)
      gload_lds16(xT + pOffs[i] + s * C1c, &Bs[s][i * 2048 + ldsW]);
  }
  // publish steps 0 AND 1 (leave only step-2's 8 loads outstanding)
  asm volatile("s_waitcnt vmcnt(8)" ::: "memory");
  __builtin_amdgcn_s_barrier();

  // rolling prefetch state for step kn = kk + 3
  int kwn = 3, qn = 0, khn = 0;
  const bf16* aPre = wT + 3 * 8192;

  // fragment register double-buffer: read step-0 frags into set A
  bf16x8 afA[8], bfA[8], afB[8], bfB[8];
#pragma unroll
  for (int mi = 0; mi < 8; mi++)
    afA[mi] = *(const bf16x8*)(As[0] + aRB + mi * 512);
#pragma unroll
  for (int ni = 0; ni < 8; ni++)
    bfA[ni] = *(const bf16x8*)(Bs[0] + bRB + ni * 512);

  auto do_step = [&](bf16x8 (&afC)[8], bf16x8 (&bfC)[8],
                     bf16x8 (&afN)[8], bf16x8 (&bfN)[8],
                     const bf16* Arb, const bf16* Brb,
                     bf16* Awb, bf16* Bwb) {
    // issue gloads for step k+3 into the ring-4 write buffer (issue-early)
#pragma unroll
    for (int i = 0; i < 4; i++)
      gload_lds16(aPre + aOffs[i], Awb + i * 2048 + ldsW);
    int bOn = (khn * HP + kwn) * C1c + qn * 32;
#pragma unroll
    for (int i = 0; i < 4; i++)
      gload_lds16(xT + pOffs[i] + bOn, Bwb + i * 2048 + ldsW);
    // advance prefetch counters (kw innermost)
    kwn++; aPre += 8192;
    if (kwn == 13) {
      kwn = 0; qn++;
      if (qn == 8) {
        qn = 0; khn++;
        if (khn == 13) { khn = 0; aPre = wT; }  // tail dummies wrap to step 0
      }
    }
    // read step k+1's fragments — its buffer was published by the
    // end-of-step-k-1 barrier (loads issued at step k-2). No race.
#pragma unroll
    for (int mi = 0; mi < 8; mi++)
      afN[mi] = *(const bf16x8*)(Arb + aRB + mi * 512);
#pragma unroll
    for (int ni = 0; ni < 8; ni++)
      bfN[ni] = *(const bf16x8*)(Brb + bRB + ni * 512);
    __builtin_amdgcn_sched_barrier(0);
    // MFMA burst on step k's registers (read last step; no LDS wait needed)
    __builtin_amdgcn_s_setprio(1);
#pragma unroll
    for (int mi = 0; mi < 8; mi++)
#pragma unroll
      for (int ni = 0; ni < 8; ni++)
        acc[mi][ni] = __builtin_amdgcn_mfma_f32_16x16x32_bf16(
            afC[mi], bfC[ni], acc[mi][ni], 0, 0, 0);
    __builtin_amdgcn_s_setprio(0);
    // leave only the 8 just-issued (k+3) outstanding => k+1,k+2 landed;
    // barrier publishes them for next step's frag reads.
    asm volatile("s_waitcnt vmcnt(8)" ::: "memory");
    __builtin_amdgcn_s_barrier();
  };

#pragma unroll 1
  for (int kk = 0; kk < KSTEPS2; kk += 4) {
    do_step(afA, bfA, afB, bfB, As[1], Bs[1], As[3], Bs[3]);
    do_step(afB, bfB, afA, bfA, As[2], Bs[2], As[0], Bs[0]);
    do_step(afA, bfA, afB, bfB, As[3], Bs[3], As[1], Bs[1]);
    do_step(afB, bfB, afA, bfA, As[0], Bs[0], As[2], Bs[2]);
  }
  // (KSTEPS2 = 1352 = 4*338: loop covers all steps; final next-frag reads
  //  and prefetches are harmless wrapped dummies, never consumed)

  // --- epilogue: BN + SiLU, fp32 NCHW stores ---
  // C/D layout (16x16): col = lane&15, row = (lane>>4)*4 + reg
  const int colL = lane & 15;
  const int quad = lane >> 4;
#pragma unroll
  for (int ni = 0; ni < 8; ni++) {
    int pix = pixbase + wn * 128 + ni * 16 + colL;
    int n = pix / (HH * WW);
    int rr = pix - n * (HH * WW);
    int oh = rr / WW;
    int ow = rr - oh * WW;
    size_t obase = (size_t)n * C2c * (HH * WW) + (size_t)oh * WW + ow;
#pragma unroll
    for (int mi = 0; mi < 8; mi++) {
      int rowb = wm * 128 + mi * 16 + quad * 4;
#pragma unroll
      for (int r = 0; r < 4; r++) {
        int rowl = rowb + r;
        float v = acc[mi][ni][r];
        v = v * sS[rowl] + sB[rowl];
        float o = v / (1.f + __expf(-v));
        out[obase + (size_t)rowl * (HH * WW)] = o;
      }
    }
  }
}

// ---------------------------------------------------------------------------
extern "C" void kernel_launch(void* const* d_in, const int* in_sizes, int n_in,
                              void* d_out, int out_size, void* d_ws, size_t ws_size,
                              hipStream_t stream) {
  const float* x     = (const float*)d_in[0];
  const float* w     = (const float*)d_in[1];
  const float* gamma = (const float*)d_in[2];
  const float* beta  = (const float*)d_in[3];
  const float* rmean = (const float*)d_in[4];
  const float* rvar  = (const float*)d_in[5];
  float* out = (float*)d_out;

  bf16* xT = (bf16*)d_ws;
  bf16* wT = xT + XT_ELEMS;

  if (ws_size < (XT_ELEMS + WT_ELEMS) * sizeof(bf16)) return;  // need ~57.3 MiB

  xform_x<<<NBAT * HP, 256, 0, stream>>>(x, xT);
  xform_w<<<(KSTEPS2 * 256 * 4) / 256, 256, 0, stream>>>(w, wT);
  conv_mfma<<<PIXTILES, 256, 0, stream>>>(xT, wT, gamma, beta, rmean, rvar, out);
}

// Round 7
// 2511.225 us; speedup vs baseline: 1.1174x; 1.1174x over previous
//
#include <hip/hip_runtime.h>
#include <hip/hip_bf16.h>

// Problem constants
#define C1c 256
#define C2c 256
#define NBAT 16
#define HH 56
#define WW 56
#define KS 13
#define PADc 6
#define HP 68                    // 56 + 2*6
#define NPIX (NBAT*HH*WW)        // 50176
#define PIXTILES 196             // NPIX / 256
#define KSTEPS2 1352             // 169 * 8 steps of BK=32, order (kh, q, kw)

typedef __bf16 bf16;
typedef bf16 bf16x8 __attribute__((ext_vector_type(8)));
typedef float floatx4 __attribute__((ext_vector_type(4)));

// Workspace layout (bf16):
//   xT : [NBAT*HP*HP][C1]          = 18,939,904 elems (37,879,808 B)
//   wT : [1352][256][32]           = 11,075,584 elems (22,151,168 B)
#define XT_ELEMS ((size_t)NBAT*HP*HP*C1c)
#define WT_ELEMS ((size_t)KSTEPS2*256*32)

// ---------------------------------------------------------------------------
// Pre-pass 1: x (N,C,H,W) fp32 -> xT [(n*68+hp)*68+wp][c1] bf16, padded.
// ---------------------------------------------------------------------------
__global__ __launch_bounds__(256) void xform_x(const float* __restrict__ x,
                                               bf16* __restrict__ xT) {
  __shared__ bf16 tile[56][258];
  const int tid = threadIdx.x;
  const int n = blockIdx.x / HP;
  const int hp = blockIdx.x - n * HP;
  const int ih = hp - PADc;
  const size_t pos_base = (size_t)(n * HP + hp) * HP * C1c;

  if (ih < 0 || ih >= HH) {
#pragma unroll 1
    for (int i = tid; i < HP * 32; i += 256) {
      int wp = i >> 5, g = i & 31;
      *(uint4*)(xT + pos_base + wp * C1c + g * 8) = (uint4){0u, 0u, 0u, 0u};
    }
    return;
  }

  const int wave = tid >> 6, lane = tid & 63;
#pragma unroll 4
  for (int i = 0; i < 64; ++i) {
    int c = i * 4 + wave;                       // covers 0..255 exactly
    if (lane < WW) {
      float v = x[(((size_t)n * C1c + c) * HH + ih) * WW + lane];
      tile[lane][c] = (bf16)v;
    }
  }
  __syncthreads();

#pragma unroll 1
  for (int i = tid; i < HP * 32; i += 256) {
    int wp = i >> 5, g = i & 31;
    int iw = wp - PADc;
    uint4 o;
    if (iw >= 0 && iw < WW) {
      const uint* lp = (const uint*)&tile[iw][g * 8];   // dword-aligned
      o.x = lp[0]; o.y = lp[1]; o.z = lp[2]; o.w = lp[3];
    } else {
      o = (uint4){0u, 0u, 0u, 0u};
    }
    *(uint4*)(xT + pos_base + wp * C1c + g * 8) = o;
  }
}

// ---------------------------------------------------------------------------
// Pre-pass 2: w (C2,C1,13,13) fp32 -> wT [kk][c2][32] bf16
//   kk = (kh*8 + q)*13 + kw,  c1 = q*32 + e   (kw innermost for xT L2 reuse)
//   NOTE: this layout is fragment-contiguous: lane (c2=row, kq granule)
//   reads 16B at kk*8192 + row*32 + kq*8 — A-frags load straight from L2.
// ---------------------------------------------------------------------------
__global__ __launch_bounds__(256) void xform_w(const float* __restrict__ w,
                                               bf16* __restrict__ wT) {
  int j = blockIdx.x * 256 + threadIdx.x;   // KSTEPS2*256*4 threads
  int part = j & 3;
  int c2 = (j >> 2) & 255;
  int kk = j >> 10;            // 0..1351
  int kw = kk % 13;
  int t = kk / 13;
  int q = t & 7;
  int kh = t >> 3;
  int c1 = q * 32 + part * 8;
  const float* wp = w + ((size_t)c2 * C1c + c1) * (KS * KS) + kh * KS + kw;
  bf16x8 v;
#pragma unroll
  for (int i = 0; i < 8; i++) v[i] = (bf16)wp[(size_t)i * KS * KS];
  *(bf16x8*)(wT + (size_t)j * 8) = v;
}

// ---------------------------------------------------------------------------
// Main: implicit-GEMM conv + BN + SiLU.
//   Block tile: 256 c2 x 256 pixels, BK=32, 8 waves (2M x 4N), per-wave
//   128x64 (8x4 mfma_16x16x32), acc = 128 AGPR.
//   KEY CHANGE vs R3: A (weights) never touches LDS. A-fragments are loaded
//   global->VGPR directly from wT (fragment-contiguous layout; 22 MB = L3
//   resident, 4 waves/block share each row-half -> L2 serves duplicates).
//   A-frags are register double-buffered (distance 1). B (pixels) keeps the
//   R3-proven LDS ring-3 path (distance 2, XOR source swizzle, 0 conflicts).
//   LDS traffic/step: 48 KB (was 128 KB) ~ 500 cyc < 1242-cyc MFMA floor.
//   Step k: {8 A-loads(k+1, plain) -> 2 B gload_lds(k+2) -> 4 bfr ds_reads(k)
//            -> sched_barrier -> setprio(1) 32 MFMA setprio(0)
//            -> vmcnt(10) (exactly the 10 VMEM issued this step remain
//               => B(k+1) drained) -> s_barrier (publish)}.
//   Regs: 128 acc + 64 afA/afB + 16 bfr + ~30 addr ~ 235 <= 256 (2 w/SIMD).
//   Grid = 196 blocks, bijective XCD swizzle (q=24, r=4).
// ---------------------------------------------------------------------------
__device__ __forceinline__ void gload_lds16(const bf16* g, bf16* l) {
  __builtin_amdgcn_global_load_lds(
      (const __attribute__((address_space(1))) void*)(g),
      (__attribute__((address_space(3))) void*)(l),
      16, 0, 0);
}

__global__ __launch_bounds__(512, 2) void conv_mfma(
    const bf16* __restrict__ xT, const bf16* __restrict__ wT,
    const float* __restrict__ gamma, const float* __restrict__ beta,
    const float* __restrict__ rmean, const float* __restrict__ rvar,
    float* __restrict__ out) {
  __shared__ __attribute__((aligned(16))) bf16 Bs[3][256 * 32];
  __shared__ float sS[256];
  __shared__ float sB[256];

  const int tid = threadIdx.x;
  const int lane = tid & 63;
  const int wave = tid >> 6;           // 0..7
  const int wm = wave >> 2, wn = wave & 3;

  // bijective XCD swizzle over 196 workgroups: q=24, r=4
  const int orig = blockIdx.x;
  const int xcd = orig & 7, kb = orig >> 3;
  const int pixt = (xcd < 4 ? xcd * 25 : 100 + (xcd - 4) * 24) + kb;
  const int pixbase = pixt * 256;

  // BN scale/bias for all 256 c2 rows
  if (tid < 256) {
    float s = gamma[tid] * rsqrtf(rvar[tid] + 1e-5f);
    sS[tid] = s;
    sB[tid] = beta[tid] - rmean[tid] * s;
  }
  __syncthreads();

  // --- B staging lane constants (XOR-swizzled source granule; R3-proven) ---
  const int part = tid & 3;                  // LDS slot within 64B row
  const int row0 = tid >> 2;                 // 0..127: row within 128-row issue
  const int srcg = (part ^ ((row0 >> 1) & 3)) * 8;  // source granule elems

  // B: issue l covers pixels [pixbase + l*128, +128)
  int pOff0, pOff1;
  {
    int pix = pixbase + row0;
    int n = pix / (HH * WW);
    int rr = pix - n * (HH * WW);
    int oh = rr / WW;
    int ow = rr - oh * WW;
    pOff0 = ((n * HP + oh) * HP + ow) * C1c + srcg;
    pix += 128;
    n = pix / (HH * WW);
    rr = pix - n * (HH * WW);
    oh = rr / WW;
    ow = rr - oh * WW;
    pOff1 = ((n * HP + oh) * HP + ow) * C1c + srcg;
  }

  // per-wave LDS destination base, in elems (gload dest = base + lane*16B)
  const int ldsA0 = wave * 512;

  // fragment-read lane constants
  const int mrow = lane & 15;
  const int kq = lane >> 4;                        // k granule (0..3)
  // B LDS read: XOR swizzle matching staging (proven conflict-free)
  const int g0 = (kq ^ ((mrow >> 1) & 3)) * 8;
  const int bRB = (wn * 64 + mrow) * 32 + g0;      // + ni*512
  // A global frag offset (natural layout, no swizzle): elems
  const int aLane = (wm * 128 + mrow) * 32 + kq * 8;   // + mi*512

  floatx4 acc[8][4];
#pragma unroll
  for (int mi = 0; mi < 8; mi++)
#pragma unroll
    for (int ni = 0; ni < 4; ni++) acc[mi][ni] = (floatx4){0.f, 0.f, 0.f, 0.f};

  // prologue: stage B for steps 0,1 (ring bufs 0,1); load A-frags step 0
  gload_lds16(xT + pOff0, &Bs[0][ldsA0]);
  gload_lds16(xT + pOff1, &Bs[0][4096 + ldsA0]);
  gload_lds16(xT + pOff0 + C1c, &Bs[1][ldsA0]);    // step1: kw=1
  gload_lds16(xT + pOff1 + C1c, &Bs[1][4096 + ldsA0]);

  bf16x8 afA[8], afB[8];
#pragma unroll
  for (int mi = 0; mi < 8; mi++)
    afA[mi] = *(const bf16x8*)(wT + aLane + mi * 512);

  // B0 drained (leave B1's 2 + A's 8 = 10 outstanding), publish
  asm volatile("s_waitcnt vmcnt(10)" ::: "memory");
  __builtin_amdgcn_s_barrier();

  // rolling B prefetch state for step kn = kk + 2 (kw innermost)
  int kwn = 2, qn = 0, khn = 0;
  // rolling A-frag pointer for step k+1
  const bf16* aPreF = wT + 8192;
  int slabA = 1;

  auto do_step = [&](bf16x8 (&afC)[8], bf16x8 (&afN)[8],
                     const bf16* Bc, bf16* Bwb) {
    // A-frags for step k+1 (global->VGPR; compiler inserts the vmcnt
    // before their first MFMA use next step)
#pragma unroll
    for (int mi = 0; mi < 8; mi++)
      afN[mi] = *(const bf16x8*)(aPreF + aLane + mi * 512);
    aPreF += 8192;
    if (++slabA == KSTEPS2) { slabA = 0; aPreF = wT; }  // tail dummy wrap

    // B staging for step k+2 into ring buffer
    int bOn = (khn * HP + kwn) * C1c + qn * 32;
    gload_lds16(xT + pOff0 + bOn, Bwb + ldsA0);
    gload_lds16(xT + pOff1 + bOn, Bwb + 4096 + ldsA0);
    kwn++;
    if (kwn == 13) {
      kwn = 0; qn++;
      if (qn == 8) {
        qn = 0; khn++;
        if (khn == 13) khn = 0;   // tail dummies wrap to step 0
      }
    }

    // B fragments for THIS step (published by last step's barrier)
    bf16x8 bfr[4];
#pragma unroll
    for (int ni = 0; ni < 4; ni++)
      bfr[ni] = *(const bf16x8*)(Bc + bRB + ni * 512);
    __builtin_amdgcn_sched_barrier(0);

    // MFMA burst: A regs preloaded last step, B regs just read
    __builtin_amdgcn_s_setprio(1);
#pragma unroll
    for (int mi = 0; mi < 8; mi++)
#pragma unroll
      for (int ni = 0; ni < 4; ni++)
        acc[mi][ni] = __builtin_amdgcn_mfma_f32_16x16x32_bf16(
            afC[mi], bfr[ni], acc[mi][ni], 0, 0, 0);
    __builtin_amdgcn_s_setprio(0);

    // exactly 10 VMEM issued this step => vmcnt(10) drains B(k+1);
    // barrier publishes it for next step's bfr reads.
    asm volatile("s_waitcnt vmcnt(10)" ::: "memory");
    __builtin_amdgcn_s_barrier();
  };

  // 6-step period: B ring mod 3, A-frag set mod 2. 1350 = 6*225.
#pragma unroll 1
  for (int kk = 0; kk < KSTEPS2 - 2; kk += 6) {
    do_step(afA, afB, Bs[0], Bs[2]);
    do_step(afB, afA, Bs[1], Bs[0]);
    do_step(afA, afB, Bs[2], Bs[1]);
    do_step(afB, afA, Bs[0], Bs[2]);
    do_step(afA, afB, Bs[1], Bs[0]);
    do_step(afB, afA, Bs[2], Bs[1]);
  }
  // tail: k=1350 (Bs[0], afA), k=1351 (Bs[1], afB); prefetches are dummies
  do_step(afA, afB, Bs[0], Bs[2]);
  do_step(afB, afA, Bs[1], Bs[0]);

  // --- epilogue: BN + SiLU, fp32 NCHW stores ---
  // C/D layout (16x16): col = lane&15 (pixel), row = (lane>>4)*4 + reg (c2)
  const int colL = lane & 15;
  const int quad = lane >> 4;
#pragma unroll
  for (int ni = 0; ni < 4; ni++) {
    int pix = pixbase + wn * 64 + ni * 16 + colL;
    int n = pix / (HH * WW);
    int rr = pix - n * (HH * WW);
    int oh = rr / WW;
    int ow = rr - oh * WW;
    size_t obase = (size_t)n * C2c * (HH * WW) + (size_t)oh * WW + ow;
#pragma unroll
    for (int mi = 0; mi < 8; mi++) {
      int rowb = wm * 128 + mi * 16 + quad * 4;
#pragma unroll
      for (int r = 0; r < 4; r++) {
        int rowl = rowb + r;
        float v = acc[mi][ni][r];
        v = v * sS[rowl] + sB[rowl];
        float o = v / (1.f + __expf(-v));
        out[obase + (size_t)rowl * (HH * WW)] = o;
      }
    }
  }
}

// ---------------------------------------------------------------------------
extern "C" void kernel_launch(void* const* d_in, const int* in_sizes, int n_in,
                              void* d_out, int out_size, void* d_ws, size_t ws_size,
                              hipStream_t stream) {
  const float* x     = (const float*)d_in[0];
  const float* w     = (const float*)d_in[1];
  const float* gamma = (const float*)d_in[2];
  const float* beta  = (const float*)d_in[3];
  const float* rmean = (const float*)d_in[4];
  const float* rvar  = (const float*)d_in[5];
  float* out = (float*)d_out;

  bf16* xT = (bf16*)d_ws;
  bf16* wT = xT + XT_ELEMS;

  if (ws_size < (XT_ELEMS + WT_ELEMS) * sizeof(bf16)) return;  // need ~57.3 MiB

  xform_x<<<NBAT * HP, 256, 0, stream>>>(x, xT);
  xform_w<<<(KSTEPS2 * 256 * 4) / 256, 256, 0, stream>>>(w, wT);
  conv_mfma<<<PIXTILES, 512, 0, stream>>>(xT, wT, gamma, beta, rmean, rvar, out);
}

// Round 8
// 1225.550 us; speedup vs baseline: 2.2896x; 2.0491x over previous
//
#include <hip/hip_runtime.h>
#include <hip/hip_bf16.h>

// Problem constants
#define C1c 256
#define C2c 256
#define NBAT 16
#define HH 56
#define WW 56
#define KS 13
#define PADc 6
#define HP 68                    // 56 + 2*6
#define NPIX (NBAT*HH*WW)        // 50176
#define PIXTILES 196             // NPIX / 256
#define KSTEPS2 1352             // 169 * 8 steps of BK=32, order (kh, q, kw)

typedef __bf16 bf16;
typedef bf16 bf16x8 __attribute__((ext_vector_type(8)));
typedef float floatx4 __attribute__((ext_vector_type(4)));

// Workspace layout (bf16):
//   xT : [NBAT*HP*HP][C1]          = 18,939,904 elems (37,879,808 B)
//   wT : [1352][256][32]           = 11,075,584 elems (22,151,168 B)
#define XT_ELEMS ((size_t)NBAT*HP*HP*C1c)
#define WT_ELEMS ((size_t)KSTEPS2*256*32)

// ---------------------------------------------------------------------------
// Pre-pass 1: x (N,C,H,W) fp32 -> xT [(n*68+hp)*68+wp][c1] bf16, padded.
// ---------------------------------------------------------------------------
__global__ __launch_bounds__(256) void xform_x(const float* __restrict__ x,
                                               bf16* __restrict__ xT) {
  __shared__ bf16 tile[56][258];
  const int tid = threadIdx.x;
  const int n = blockIdx.x / HP;
  const int hp = blockIdx.x - n * HP;
  const int ih = hp - PADc;
  const size_t pos_base = (size_t)(n * HP + hp) * HP * C1c;

  if (ih < 0 || ih >= HH) {
#pragma unroll 1
    for (int i = tid; i < HP * 32; i += 256) {
      int wp = i >> 5, g = i & 31;
      *(uint4*)(xT + pos_base + wp * C1c + g * 8) = (uint4){0u, 0u, 0u, 0u};
    }
    return;
  }

  const int wave = tid >> 6, lane = tid & 63;
#pragma unroll 4
  for (int i = 0; i < 64; ++i) {
    int c = i * 4 + wave;                       // covers 0..255 exactly
    if (lane < WW) {
      float v = x[(((size_t)n * C1c + c) * HH + ih) * WW + lane];
      tile[lane][c] = (bf16)v;
    }
  }
  __syncthreads();

#pragma unroll 1
  for (int i = tid; i < HP * 32; i += 256) {
    int wp = i >> 5, g = i & 31;
    int iw = wp - PADc;
    uint4 o;
    if (iw >= 0 && iw < WW) {
      const uint* lp = (const uint*)&tile[iw][g * 8];   // dword-aligned
      o.x = lp[0]; o.y = lp[1]; o.z = lp[2]; o.w = lp[3];
    } else {
      o = (uint4){0u, 0u, 0u, 0u};
    }
    *(uint4*)(xT + pos_base + wp * C1c + g * 8) = o;
  }
}

// ---------------------------------------------------------------------------
// Pre-pass 2: w (C2,C1,13,13) fp32 -> wT [kk][c2][32] bf16
//   kk = (kh*8 + q)*13 + kw,  c1 = q*32 + e   (kw innermost for xT L2 reuse)
// ---------------------------------------------------------------------------
__global__ __launch_bounds__(256) void xform_w(const float* __restrict__ w,
                                               bf16* __restrict__ wT) {
  int j = blockIdx.x * 256 + threadIdx.x;   // KSTEPS2*256*4 threads
  int part = j & 3;
  int c2 = (j >> 2) & 255;
  int kk = j >> 10;            // 0..1351
  int kw = kk % 13;
  int t = kk / 13;
  int q = t & 7;
  int kh = t >> 3;
  int c1 = q * 32 + part * 8;
  const float* wp = w + ((size_t)c2 * C1c + c1) * (KS * KS) + kh * KS + kw;
  bf16x8 v;
#pragma unroll
  for (int i = 0; i < 8; i++) v[i] = (bf16)wp[(size_t)i * KS * KS];
  *(bf16x8*)(wT + (size_t)j * 8) = v;
}

// ---------------------------------------------------------------------------
// Main: implicit-GEMM conv + BN + SiLU.
//   Block tile: 256 c2 x 256 pixels, BK=32, 8 waves (2M x 4N), per-wave
//   128x64 (8x4 mfma_16x16x32), acc = 128 AGPR. Ring-3 LDS, dist-2 prefetch,
//   counted vmcnt(4). All R3-proven (0 conflicts, no spill).
//   R8 change (m201-faithful cadence): s_barrier BETWEEN each phase's
//   ds_reads and its MFMA cluster. While a wave waits at the barrier its
//   reads are in flight; the 2 waves/SIMD leave de-phased, so one wave's
//   reads overlap the other's MFMA tail (the anti-phase mechanism that
//   gives m201 62% MfmaUtil at identical occupancy). sched_barrier(0) on
//   both sides of each s_barrier pins the placement against the scheduler.
//   Step: {8 reads + 2 A-gloads | BAR | 16 MFMA (mi0-3)}
//         {4 reads + 2 B-gloads | BAR | 16 MFMA (mi4-7)}
//         {vmcnt(4) | BAR (publish k+1)}
//   Grid = 196 blocks, bijective XCD swizzle (q=24, r=4).
// ---------------------------------------------------------------------------
__device__ __forceinline__ void gload_lds16(const bf16* g, bf16* l) {
  __builtin_amdgcn_global_load_lds(
      (const __attribute__((address_space(1))) void*)(g),
      (__attribute__((address_space(3))) void*)(l),
      16, 0, 0);
}

__global__ __launch_bounds__(512, 2) void conv_mfma(
    const bf16* __restrict__ xT, const bf16* __restrict__ wT,
    const float* __restrict__ gamma, const float* __restrict__ beta,
    const float* __restrict__ rmean, const float* __restrict__ rvar,
    float* __restrict__ out) {
  __shared__ __attribute__((aligned(16))) bf16 As[3][256 * 32];
  __shared__ __attribute__((aligned(16))) bf16 Bs[3][256 * 32];
  __shared__ float sS[256];
  __shared__ float sB[256];

  const int tid = threadIdx.x;
  const int lane = tid & 63;
  const int wave = tid >> 6;           // 0..7
  const int wm = wave >> 2, wn = wave & 3;

  // bijective XCD swizzle over 196 workgroups: q=24, r=4
  const int orig = blockIdx.x;
  const int xcd = orig & 7, kb = orig >> 3;
  const int pixt = (xcd < 4 ? xcd * 25 : 100 + (xcd - 4) * 24) + kb;
  const int pixbase = pixt * 256;

  // BN scale/bias for all 256 c2 rows
  if (tid < 256) {
    float s = gamma[tid] * rsqrtf(rvar[tid] + 1e-5f);
    sS[tid] = s;
    sB[tid] = beta[tid] - rmean[tid] * s;
  }
  __syncthreads();

  // --- staging lane constants (XOR-swizzled source granule) ---
  const int part = tid & 3;                  // LDS slot within 64B row
  const int row0 = tid >> 2;                 // 0..127: row within 128-row issue
  const int srcg = (part ^ ((row0 >> 1) & 3)) * 8;  // source granule elems

  // A: issue l covers c2 rows [l*128, l*128+128)
  const int aOff0 = row0 * 32 + srcg;
  const int aOff1 = aOff0 + 128 * 32;

  // B: issue l covers pixels [pixbase + l*128, +128)
  int pOff0, pOff1;
  {
    int pix = pixbase + row0;
    int n = pix / (HH * WW);
    int rr = pix - n * (HH * WW);
    int oh = rr / WW;
    int ow = rr - oh * WW;
    pOff0 = ((n * HP + oh) * HP + ow) * C1c + srcg;
    pix += 128;
    n = pix / (HH * WW);
    rr = pix - n * (HH * WW);
    oh = rr / WW;
    ow = rr - oh * WW;
    pOff1 = ((n * HP + oh) * HP + ow) * C1c + srcg;
  }

  // per-wave LDS destination base, in elems (gload dest = base + lane*16B)
  const int ldsA0 = wave * 512;

  // fragment-read lane constants (R1/R3 addressing — proven conflict-free)
  const int mrow = lane & 15;
  const int kq = lane >> 4;                        // source k granule (0..3)
  const int g0 = (kq ^ ((mrow >> 1) & 3)) * 8;     // swizzled LDS offset
  const int aRB = (wm * 128 + mrow) * 32 + g0;     // + mi*512
  const int bRB = (wn * 64 + mrow) * 32 + g0;      // + ni*512

  floatx4 acc[8][4];
#pragma unroll
  for (int mi = 0; mi < 8; mi++)
#pragma unroll
    for (int ni = 0; ni < 4; ni++) acc[mi][ni] = (floatx4){0.f, 0.f, 0.f, 0.f};

  // prologue: stage step 0 -> buf0, step 1 -> buf1  (order A,A,B,B per step)
  gload_lds16(wT + aOff0, &As[0][ldsA0]);
  gload_lds16(wT + aOff1, &As[0][4096 + ldsA0]);
  gload_lds16(xT + pOff0, &Bs[0][ldsA0]);
  gload_lds16(xT + pOff1, &Bs[0][4096 + ldsA0]);
  gload_lds16(wT + 8192 + aOff0, &As[1][ldsA0]);
  gload_lds16(wT + 8192 + aOff1, &As[1][4096 + ldsA0]);
  gload_lds16(xT + pOff0 + C1c, &Bs[1][ldsA0]);    // step1: kw=1
  gload_lds16(xT + pOff1 + C1c, &Bs[1][4096 + ldsA0]);
  asm volatile("s_waitcnt vmcnt(4)" ::: "memory");  // step-0 loads landed
  __builtin_amdgcn_s_barrier();

  // rolling prefetch state for step kn = kk + 2
  int kwn = 2, qn = 0, khn = 0;
  const bf16* aPre = wT + 2 * 8192;

  auto do_step = [&](const bf16* Ac, const bf16* Bc, bf16* An, bf16* Bn) {
    // entering: this step's buffer landed & visible to all waves

    bf16x8 af[8], bfr[4];
    // ---- phase 0: reads a0-3 + all b (8 ds_reads) + stage A(k+2) ----
#pragma unroll
    for (int mi = 0; mi < 4; mi++)
      af[mi] = *(const bf16x8*)(Ac + aRB + mi * 512);
#pragma unroll
    for (int ni = 0; ni < 4; ni++)
      bfr[ni] = *(const bf16x8*)(Bc + bRB + ni * 512);
    gload_lds16(aPre + aOff0, An + ldsA0);
    gload_lds16(aPre + aOff1, An + 4096 + ldsA0);
    __builtin_amdgcn_sched_barrier(0);
    __builtin_amdgcn_s_barrier();          // anti-phase barrier: reads in
    __builtin_amdgcn_sched_barrier(0);     // flight while waiting here
    __builtin_amdgcn_s_setprio(1);
#pragma unroll
    for (int mi = 0; mi < 4; mi++)
#pragma unroll
      for (int ni = 0; ni < 4; ni++)
        acc[mi][ni] = __builtin_amdgcn_mfma_f32_16x16x32_bf16(
            af[mi], bfr[ni], acc[mi][ni], 0, 0, 0);
    __builtin_amdgcn_s_setprio(0);

    // ---- phase 1: reads a4-7 (4 ds_reads) + stage B(k+2) ----
#pragma unroll
    for (int mi = 4; mi < 8; mi++)
      af[mi] = *(const bf16x8*)(Ac + aRB + mi * 512);
    int bOn = (khn * HP + kwn) * C1c + qn * 32;
    gload_lds16(xT + pOff0 + bOn, Bn + ldsA0);
    gload_lds16(xT + pOff1 + bOn, Bn + 4096 + ldsA0);
    // advance prefetch counters (kw innermost)
    kwn++; aPre += 8192;
    if (kwn == 13) {
      kwn = 0; qn++;
      if (qn == 8) {
        qn = 0; khn++;
        if (khn == 13) { khn = 0; aPre = wT; }  // tail dummies wrap to step 0
      }
    }
    __builtin_amdgcn_sched_barrier(0);
    __builtin_amdgcn_s_barrier();          // anti-phase barrier #2
    __builtin_amdgcn_sched_barrier(0);
    __builtin_amdgcn_s_setprio(1);
#pragma unroll
    for (int mi = 4; mi < 8; mi++)
#pragma unroll
      for (int ni = 0; ni < 4; ni++)
        acc[mi][ni] = __builtin_amdgcn_mfma_f32_16x16x32_bf16(
            af[mi], bfr[ni], acc[mi][ni], 0, 0, 0);
    __builtin_amdgcn_s_setprio(0);

    // ---- publish: k+1's loads landed (8 in flight -> keep this step's 4) --
    asm volatile("s_waitcnt vmcnt(4)" ::: "memory");
    __builtin_amdgcn_s_barrier();
  };

#pragma unroll 1
  for (int kk = 0; kk < KSTEPS2 - 2; kk += 3) {
    do_step(As[0], Bs[0], As[2], Bs[2]);
    do_step(As[1], Bs[1], As[0], Bs[0]);
    do_step(As[2], Bs[2], As[1], Bs[1]);
  }
  // tail: steps 1350 (buf0), 1351 (buf1); prefetches are harmless dummies
  do_step(As[0], Bs[0], As[2], Bs[2]);
  do_step(As[1], Bs[1], As[0], Bs[0]);

  // --- epilogue: BN + SiLU, fp32 NCHW stores ---
  // C/D layout (16x16): col = lane&15, row = (lane>>4)*4 + reg
  const int colL = lane & 15;
  const int quad = lane >> 4;
#pragma unroll
  for (int ni = 0; ni < 4; ni++) {
    int pix = pixbase + wn * 64 + ni * 16 + colL;
    int n = pix / (HH * WW);
    int rr = pix - n * (HH * WW);
    int oh = rr / WW;
    int ow = rr - oh * WW;
    size_t obase = (size_t)n * C2c * (HH * WW) + (size_t)oh * WW + ow;
#pragma unroll
    for (int mi = 0; mi < 8; mi++) {
      int rowb = wm * 128 + mi * 16 + quad * 4;
#pragma unroll
      for (int r = 0; r < 4; r++) {
        int rowl = rowb + r;
        float v = acc[mi][ni][r];
        v = v * sS[rowl] + sB[rowl];
        float o = v / (1.f + __expf(-v));
        out[obase + (size_t)rowl * (HH * WW)] = o;
      }
    }
  }
}

// ---------------------------------------------------------------------------
extern "C" void kernel_launch(void* const* d_in, const int* in_sizes, int n_in,
                              void* d_out, int out_size, void* d_ws, size_t ws_size,
                              hipStream_t stream) {
  const float* x     = (const float*)d_in[0];
  const float* w     = (const float*)d_in[1];
  const float* gamma = (const float*)d_in[2];
  const float* beta  = (const float*)d_in[3];
  const float* rmean = (const float*)d_in[4];
  const float* rvar  = (const float*)d_in[5];
  float* out = (float*)d_out;

  bf16* xT = (bf16*)d_ws;
  bf16* wT = xT + XT_ELEMS;

  if (ws_size < (XT_ELEMS + WT_ELEMS) * sizeof(bf16)) return;  // need ~57.3 MiB

  xform_x<<<NBAT * HP, 256, 0, stream>>>(x, xT);
  xform_w<<<(KSTEPS2 * 256 * 4) / 256, 256, 0, stream>>>(w, wT);
  conv_mfma<<<PIXTILES, 512, 0, stream>>>(xT, wT, gamma, beta, rmean, rvar, out);
}

// Round 9
// 1216.532 us; speedup vs baseline: 2.3066x; 1.0074x over previous
//
#include <hip/hip_runtime.h>
#include <hip/hip_bf16.h>

// Problem constants
#define C1c 256
#define C2c 256
#define NBAT 16
#define HH 56
#define WW 56
#define KS 13
#define PADc 6
#define HP 68                    // 56 + 2*6
#define NPIX (NBAT*HH*WW)        // 50176 = 224 * 224
#define PIXTILES 224             // NPIX / 224-pixel tiles
#define PTILE 224                // pixels per block tile
#define KSTEPS2 1352             // 169 * 8 steps of BK=32, order (kh, q, kw)

typedef __bf16 bf16;
typedef bf16 bf16x8 __attribute__((ext_vector_type(8)));
typedef float floatx4 __attribute__((ext_vector_type(4)));

// Workspace layout (bf16):
//   xT : [NBAT*HP*HP][C1]          = 18,939,904 elems (37,879,808 B)
//   wT : [1352][256][32]           = 11,075,584 elems (22,151,168 B)
#define XT_ELEMS ((size_t)NBAT*HP*HP*C1c)
#define WT_ELEMS ((size_t)KSTEPS2*256*32)

// ---------------------------------------------------------------------------
// Pre-pass 1: x (N,C,H,W) fp32 -> xT [(n*68+hp)*68+wp][c1] bf16, padded.
// ---------------------------------------------------------------------------
__global__ __launch_bounds__(256) void xform_x(const float* __restrict__ x,
                                               bf16* __restrict__ xT) {
  __shared__ bf16 tile[56][258];
  const int tid = threadIdx.x;
  const int n = blockIdx.x / HP;
  const int hp = blockIdx.x - n * HP;
  const int ih = hp - PADc;
  const size_t pos_base = (size_t)(n * HP + hp) * HP * C1c;

  if (ih < 0 || ih >= HH) {
#pragma unroll 1
    for (int i = tid; i < HP * 32; i += 256) {
      int wp = i >> 5, g = i & 31;
      *(uint4*)(xT + pos_base + wp * C1c + g * 8) = (uint4){0u, 0u, 0u, 0u};
    }
    return;
  }

  const int wave = tid >> 6, lane = tid & 63;
#pragma unroll 4
  for (int i = 0; i < 64; ++i) {
    int c = i * 4 + wave;                       // covers 0..255 exactly
    if (lane < WW) {
      float v = x[(((size_t)n * C1c + c) * HH + ih) * WW + lane];
      tile[lane][c] = (bf16)v;
    }
  }
  __syncthreads();

#pragma unroll 1
  for (int i = tid; i < HP * 32; i += 256) {
    int wp = i >> 5, g = i & 31;
    int iw = wp - PADc;
    uint4 o;
    if (iw >= 0 && iw < WW) {
      const uint* lp = (const uint*)&tile[iw][g * 8];   // dword-aligned
      o.x = lp[0]; o.y = lp[1]; o.z = lp[2]; o.w = lp[3];
    } else {
      o = (uint4){0u, 0u, 0u, 0u};
    }
    *(uint4*)(xT + pos_base + wp * C1c + g * 8) = o;
  }
}

// ---------------------------------------------------------------------------
// Pre-pass 2: w (C2,C1,13,13) fp32 -> wT [kk][c2][32] bf16
//   kk = (kh*8 + q)*13 + kw,  c1 = q*32 + e   (kw innermost for xT L2 reuse)
// ---------------------------------------------------------------------------
__global__ __launch_bounds__(256) void xform_w(const float* __restrict__ w,
                                               bf16* __restrict__ wT) {
  int j = blockIdx.x * 256 + threadIdx.x;   // KSTEPS2*256*4 threads
  int part = j & 3;
  int c2 = (j >> 2) & 255;
  int kk = j >> 10;            // 0..1351
  int kw = kk % 13;
  int t = kk / 13;
  int q = t & 7;
  int kh = t >> 3;
  int c1 = q * 32 + part * 8;
  const float* wp = w + ((size_t)c2 * C1c + c1) * (KS * KS) + kh * KS + kw;
  bf16x8 v;
#pragma unroll
  for (int i = 0; i < 8; i++) v[i] = (bf16)wp[(size_t)i * KS * KS];
  *(bf16x8*)(wT + (size_t)j * 8) = v;
}

// ---------------------------------------------------------------------------
// Main: implicit-GEMM conv + BN + SiLU.
//   R9 retile: 50176 = 224*224 -> block tile 256 c2 x 224 pixels, grid 224
//   blocks = 87.5% CU coverage (was 196/256 = 76.6%). Per-step cost shrinks:
//   MFMA/CU-step 256->224, frag reads 96->88, staging 32->30 KB.
//   8 waves as 4M x 2N: per-wave 64 c2 x 112 px, acc 4x7 floatx4 = 112 AGPR,
//   af[4]+bfr[7] frags (less reg pressure than R8's 8x4).
//   B staging: 224 rows = 14 wave-issues: waves 0-6 issue 2 (rows r, r+112),
//   wave 7 issues none -> per-wave counted vmcnt (4 for w<7, 2 for w7).
//   Cadence = R8 (ring-3, dist-2 prefetch, 2-phase + publish barrier).
//   XOR swizzle slot = part ^ ((row>>1)&3) on source addresses; read keys
//   use row mod 16 and 112 % 16 == 0, so the proven 0-conflict pattern holds.
//   Grid = 224 = 8 XCD * 28: swizzle pixt = (orig&7)*28 + (orig>>3).
// ---------------------------------------------------------------------------
__device__ __forceinline__ void gload_lds16(const bf16* g, bf16* l) {
  __builtin_amdgcn_global_load_lds(
      (const __attribute__((address_space(1))) void*)(g),
      (__attribute__((address_space(3))) void*)(l),
      16, 0, 0);
}

__global__ __launch_bounds__(512, 2) void conv_mfma(
    const bf16* __restrict__ xT, const bf16* __restrict__ wT,
    const float* __restrict__ gamma, const float* __restrict__ beta,
    const float* __restrict__ rmean, const float* __restrict__ rvar,
    float* __restrict__ out) {
  __shared__ __attribute__((aligned(16))) bf16 As[3][256 * 32];
  __shared__ __attribute__((aligned(16))) bf16 Bs[3][PTILE * 32];
  __shared__ float sS[256];
  __shared__ float sB[256];

  const int tid = threadIdx.x;
  const int lane = tid & 63;
  const int wave = tid >> 6;           // 0..7
  const int wm = wave >> 1, wn = wave & 1;   // 4M x 2N

  // XCD swizzle over 224 workgroups (224 = 8*28, exact)
  const int orig = blockIdx.x;
  const int pixt = (orig & 7) * 28 + (orig >> 3);
  const int pixbase = pixt * PTILE;

  // BN scale/bias for all 256 c2 rows
  if (tid < 256) {
    float s = gamma[tid] * rsqrtf(rvar[tid] + 1e-5f);
    sS[tid] = s;
    sB[tid] = beta[tid] - rmean[tid] * s;
  }
  __syncthreads();

  // --- staging lane constants (XOR-swizzled source granule) ---
  const int part = tid & 3;                  // LDS slot within 64B row
  const int row0 = tid >> 2;                 // 0..127
  const int srcg = (part ^ ((row0 >> 1) & 3)) * 8;  // source granule elems

  // A: issue l covers c2 rows [l*128, +128); all 8 waves
  const int aOff0 = row0 * 32 + srcg;
  const int aOff1 = aOff0 + 128 * 32;

  // B: waves 0-6 (row0 < 112): issue0 rows [0,112), issue1 rows [112,224)
  const bool bstage = (wave < 7);
  int pOff0 = 0, pOff1 = 0;
  if (bstage) {
    int pix = pixbase + row0;
    int n = pix / (HH * WW);
    int rr = pix - n * (HH * WW);
    int oh = rr / WW;
    int ow = rr - oh * WW;
    pOff0 = ((n * HP + oh) * HP + ow) * C1c + srcg;
    pix += 112;
    n = pix / (HH * WW);
    rr = pix - n * (HH * WW);
    oh = rr / WW;
    ow = rr - oh * WW;
    pOff1 = ((n * HP + oh) * HP + ow) * C1c + srcg;
  }

  // per-wave LDS destination bases (gload dest = base + lane*16B)
  const int ldsA0 = wave * 512;              // A issues; B issue0 (w<7)
  const int ldsB1 = 112 * 32 + wave * 512;   // B issue1 (w<7)

  // fragment-read lane constants (proven conflict-free pattern)
  const int mrow = lane & 15;
  const int kq = lane >> 4;                        // source k granule (0..3)
  const int g0 = (kq ^ ((mrow >> 1) & 3)) * 8;     // swizzled LDS offset
  const int aRB = (wm * 64 + mrow) * 32 + g0;      // + mi*512  (mi 0..3)
  const int bRB = (wn * 112 + mrow) * 32 + g0;     // + ni*512  (ni 0..6)

  floatx4 acc[4][7];
#pragma unroll
  for (int mi = 0; mi < 4; mi++)
#pragma unroll
    for (int ni = 0; ni < 7; ni++) acc[mi][ni] = (floatx4){0.f, 0.f, 0.f, 0.f};

  // prologue: stage step 0 -> buf0, step 1 -> buf1
  gload_lds16(wT + aOff0, &As[0][ldsA0]);
  gload_lds16(wT + aOff1, &As[0][4096 + ldsA0]);
  if (bstage) {
    gload_lds16(xT + pOff0, &Bs[0][ldsA0]);
    gload_lds16(xT + pOff1, &Bs[0][ldsB1]);
  }
  gload_lds16(wT + 8192 + aOff0, &As[1][ldsA0]);
  gload_lds16(wT + 8192 + aOff1, &As[1][4096 + ldsA0]);
  if (bstage) {
    gload_lds16(xT + pOff0 + C1c, &Bs[1][ldsA0]);    // step1: kw=1
    gload_lds16(xT + pOff1 + C1c, &Bs[1][ldsB1]);
  }
  // drain step-0 loads (per-wave counted), publish
  if (bstage) { asm volatile("s_waitcnt vmcnt(4)" ::: "memory"); }
  else        { asm volatile("s_waitcnt vmcnt(2)" ::: "memory"); }
  __builtin_amdgcn_s_barrier();

  // rolling prefetch state for step kn = kk + 2
  int kwn = 2, qn = 0, khn = 0;
  const bf16* aPre = wT + 2 * 8192;

  auto do_step = [&](const bf16* Ac, const bf16* Bc, bf16* An, bf16* Bn) {
    bf16x8 af[4], bfr[7];
    // ---- phase 0: reads af0-1 + all bfr (9 ds_reads) + stage A(k+2) ----
#pragma unroll
    for (int mi = 0; mi < 2; mi++)
      af[mi] = *(const bf16x8*)(Ac + aRB + mi * 512);
#pragma unroll
    for (int ni = 0; ni < 7; ni++)
      bfr[ni] = *(const bf16x8*)(Bc + bRB + ni * 512);
    gload_lds16(aPre + aOff0, An + ldsA0);
    gload_lds16(aPre + aOff1, An + 4096 + ldsA0);
    __builtin_amdgcn_sched_barrier(0);
    __builtin_amdgcn_s_barrier();
    __builtin_amdgcn_sched_barrier(0);
    __builtin_amdgcn_s_setprio(1);
#pragma unroll
    for (int mi = 0; mi < 2; mi++)
#pragma unroll
      for (int ni = 0; ni < 7; ni++)
        acc[mi][ni] = __builtin_amdgcn_mfma_f32_16x16x32_bf16(
            af[mi], bfr[ni], acc[mi][ni], 0, 0, 0);
    __builtin_amdgcn_s_setprio(0);

    // ---- phase 1: reads af2-3 + stage B(k+2) ----
#pragma unroll
    for (int mi = 2; mi < 4; mi++)
      af[mi] = *(const bf16x8*)(Ac + aRB + mi * 512);
    int bOn = (khn * HP + kwn) * C1c + qn * 32;
    if (bstage) {
      gload_lds16(xT + pOff0 + bOn, Bn + ldsA0);
      gload_lds16(xT + pOff1 + bOn, Bn + ldsB1);
    }
    // advance prefetch counters (kw innermost) — all waves
    kwn++; aPre += 8192;
    if (kwn == 13) {
      kwn = 0; qn++;
      if (qn == 8) {
        qn = 0; khn++;
        if (khn == 13) { khn = 0; aPre = wT; }  // tail dummies wrap to step 0
      }
    }
    __builtin_amdgcn_sched_barrier(0);
    __builtin_amdgcn_s_barrier();
    __builtin_amdgcn_sched_barrier(0);
    __builtin_amdgcn_s_setprio(1);
#pragma unroll
    for (int mi = 2; mi < 4; mi++)
#pragma unroll
      for (int ni = 0; ni < 7; ni++)
        acc[mi][ni] = __builtin_amdgcn_mfma_f32_16x16x32_bf16(
            af[mi], bfr[ni], acc[mi][ni], 0, 0, 0);
    __builtin_amdgcn_s_setprio(0);

    // ---- publish: drain step k+1's loads (per-wave counted) ----
    if (bstage) { asm volatile("s_waitcnt vmcnt(4)" ::: "memory"); }
    else        { asm volatile("s_waitcnt vmcnt(2)" ::: "memory"); }
    __builtin_amdgcn_s_barrier();
  };

#pragma unroll 1
  for (int kk = 0; kk < KSTEPS2 - 2; kk += 3) {
    do_step(As[0], Bs[0], As[2], Bs[2]);
    do_step(As[1], Bs[1], As[0], Bs[0]);
    do_step(As[2], Bs[2], As[1], Bs[1]);
  }
  // tail: steps 1350 (buf0), 1351 (buf1); prefetches are harmless dummies
  do_step(As[0], Bs[0], As[2], Bs[2]);
  do_step(As[1], Bs[1], As[0], Bs[0]);

  // --- epilogue: BN + SiLU, fp32 NCHW stores ---
  // C/D layout (16x16): col = lane&15 (pixel), row = (lane>>4)*4 + reg (c2)
  const int colL = lane & 15;
  const int quad = lane >> 4;
#pragma unroll
  for (int ni = 0; ni < 7; ni++) {
    int pix = pixbase + wn * 112 + ni * 16 + colL;
    int n = pix / (HH * WW);
    int rr = pix - n * (HH * WW);
    int oh = rr / WW;
    int ow = rr - oh * WW;
    size_t obase = (size_t)n * C2c * (HH * WW) + (size_t)oh * WW + ow;
#pragma unroll
    for (int mi = 0; mi < 4; mi++) {
      int rowb = wm * 64 + mi * 16 + quad * 4;
#pragma unroll
      for (int r = 0; r < 4; r++) {
        int rowl = rowb + r;
        float v = acc[mi][ni][r];
        v = v * sS[rowl] + sB[rowl];
        float o = v / (1.f + __expf(-v));
        out[obase + (size_t)rowl * (HH * WW)] = o;
      }
    }
  }
}

// ---------------------------------------------------------------------------
extern "C" void kernel_launch(void* const* d_in, const int* in_sizes, int n_in,
                              void* d_out, int out_size, void* d_ws, size_t ws_size,
                              hipStream_t stream) {
  const float* x     = (const float*)d_in[0];
  const float* w     = (const float*)d_in[1];
  const float* gamma = (const float*)d_in[2];
  const float* beta  = (const float*)d_in[3];
  const float* rmean = (const float*)d_in[4];
  const float* rvar  = (const float*)d_in[5];
  float* out = (float*)d_out;

  bf16* xT = (bf16*)d_ws;
  bf16* wT = xT + XT_ELEMS;

  if (ws_size < (XT_ELEMS + WT_ELEMS) * sizeof(bf16)) return;  // need ~57.3 MiB

  xform_x<<<NBAT * HP, 256, 0, stream>>>(x, xT);
  xform_w<<<(KSTEPS2 * 256 * 4) / 256, 256, 0, stream>>>(w, wT);
  conv_mfma<<<PIXTILES, 512, 0, stream>>>(xT, wT, gamma, beta, rmean, rvar, out);
}